// Round 8
// baseline (1559.148 us; speedup 1.0000x reference)
//
#include <hip/hip_runtime.h>
#include <math.h>

// ---------------------------------------------------------------------------
// BlockAttnRes, round 8: streaming mixture -> register pressure killed.
// History: r3/r6/r7 all died of register state (live >140 -> either AGPR
// inflation -> 1 wave/SIMD, or forced budget -> scratch spill -> HBM-bound
// on spill traffic). Fix: stop holding V[NS] across layers. Sources are
// L3-resident (128 MB < 256 MB IC); stream them per layer with a 2-deep
// double buffer; recompute RMS inline. Peak live ~110 regs.
// Structure otherwise = r6 (zero-spill baseline): 128-thr/2-wave blocks,
// 16 tokens/block, per-wave N-split GEMMs, 21 KB LDS, 3 barriers/layer.
// ---------------------------------------------------------------------------

typedef float    f32x4  __attribute__((ext_vector_type(4)));
typedef __bf16   bf16x8 __attribute__((ext_vector_type(8)));
typedef unsigned short u16x8 __attribute__((ext_vector_type(8)));

#define D 128

__device__ __forceinline__ unsigned short f2bf(float f) {
  unsigned int u = __builtin_bit_cast(unsigned int, f);
  u += 0x7fffu + ((u >> 16) & 1u);          // RNE
  return (unsigned short)(u >> 16);
}

__device__ __forceinline__ float dot4(f32x4 a, f32x4 b) {
  return a.x * b.x + a.y * b.y + a.z * b.z + a.w * b.w;
}

// exact-GELU via A&S 7.1.25 erf approx (|eps|<=2.5e-5, << bf16 rounding)
__device__ __forceinline__ float fast_gelu(float x) {
  float y = fabsf(x) * 0.70710678118654752f;
  float t = 1.0f / fmaf(0.47047f, y, 1.0f);
  float P = fmaf(fmaf(0.7478556f, t, -0.0958798f), t, 0.3480242f) * t;
  float E = __expf(-y * y);
  float er = fmaf(-P, E, 1.0f);             // erf(|x|/sqrt2)
  er = copysignf(er, x);
  return 0.5f * x * (1.0f + er);
}

// ---------------------------------------------------------------------------
// Pack W1/W2 (fp32 row-major) into bf16 MFMA B-fragment order:
// frag idx = ((kk*NT + nt)*64 + lane)*8 + j holds
//   B[k = kk*32 + (lane>>4)*8 + j][n = nt*16 + (lane&15)]
// ---------------------------------------------------------------------------
__global__ __launch_bounds__(256) void pack_weights(
    const float* __restrict__ W1, const float* __restrict__ W2,
    unsigned short* __restrict__ W1p, unsigned short* __restrict__ W2p)
{
  int t = blockIdx.x * 256 + threadIdx.x;
  if (t < 16 * 128 * 256) {
    int layer = t >> 15, r = t & 32767;
    int j = r & 7, lane = (r >> 3) & 63, nt = (r >> 9) & 15, kk = (r >> 13) & 3;
    int k = kk * 32 + ((lane >> 4) << 3) + j;
    int n = (nt << 4) + (lane & 15);
    W1p[t] = f2bf(W1[(layer << 15) + (k << 8) + n]);     // W1: [128][256]
  } else {
    int t2 = t - 16 * 128 * 256;
    int layer = t2 >> 15, r = t2 & 32767;
    int j = r & 7, lane = (r >> 3) & 63, nt = (r >> 9) & 7, kk = (r >> 12) & 7;
    int k = kk * 32 + ((lane >> 4) << 3) + j;
    int n = (nt << 4) + (lane & 15);
    W2p[t2] = f2bf(W2[(layer << 15) + (k << 7) + n]);    // W2: [256][128]
  }
}

// ---------------------------------------------------------------------------
// 4-layer fused kernel, 16 tokens per 128-thread block (2 waves).
// Sources streamed from L3 each layer (double-buffered, 2x16 regs live).
// ---------------------------------------------------------------------------
template<int NS, bool LAST>
__global__ __launch_bounds__(128)
void fused4(const float* __restrict__ S0, const float* __restrict__ S1,
            const float* __restrict__ S2, const float* __restrict__ S3,
            const float* __restrict__ wv_all, const float* __restrict__ lng_all,
            const float* __restrict__ lnb_all,
            const unsigned short* __restrict__ W1p, const float* __restrict__ b1_all,
            const unsigned short* __restrict__ W2p, const float* __restrict__ b2_all,
            float* __restrict__ dst)
{
  __shared__ u16x8 A1[256];     //  4 KB  A1 fragments (16x128 bf16)
  __shared__ u16x8 A2[512];     //  8 KB  A2 fragments (16x256 bf16)
  __shared__ float SC[2112];    //  8.25 KB  16x132 f32 v-transpose scratch

  const int tid  = threadIdx.x;
  const int w2   = tid >> 6;          // pair member 0/1
  const int l    = tid & 63;
  const int tk8  = l >> 3;            // wave-local token 0..7
  const int c8   = l & 7;             // 16-col slice 0..7
  const int r    = w2 * 8 + tk8;      // pair-local token row 0..15
  const int c0   = c8 * 16;
  const int tok  = blockIdx.x * 16 + r;
  const int ln15 = l & 15, lhi = l >> 4;
  const size_t toff = (size_t)tok * D + c0;

  unsigned short* A2u = (unsigned short*)A2;
  const float* srcs[4] = {S0, S1, S2, S3};

  f32x4 part[4];
  #pragma unroll
  for (int i = 0; i < 4; ++i) part[i] = f32x4{0.f, 0.f, 0.f, 0.f};

  const int L0 = (NS - 1) * 4;

  #pragma unroll 1
  for (int ll = 0; ll < 4; ++ll) {
    const int layer = L0 + ll;

    const float* wl = wv_all + layer * D + c0;
    f32x4 wv[4];
    #pragma unroll
    for (int i = 0; i < 4; ++i) wv[i] = *(const f32x4*)(wl + 4 * i);

    // ---- mixture softmax, sources STREAMED from L3 (double-buffered) -----
    // max-free: |logit| <= ~2.6, fp32 exp safe. RMS recomputed inline.
    float denom = 0.f;
    f32x4 hacc[4];
    #pragma unroll
    for (int i = 0; i < 4; ++i) hacc[i] = f32x4{0.f, 0.f, 0.f, 0.f};

    f32x4 cur[4], nxt[4];
    #pragma unroll
    for (int i = 0; i < 4; ++i) cur[i] = *(const f32x4*)(srcs[0] + toff + 4 * i);

    #pragma unroll
    for (int s = 0; s < NS; ++s) {
      if (s + 1 < NS) {                 // prefetch next source over compute
        #pragma unroll
        for (int i = 0; i < 4; ++i) nxt[i] = *(const f32x4*)(srcs[s + 1] + toff + 4 * i);
      }
      float q = 0.f, d2 = 0.f;
      #pragma unroll
      for (int i = 0; i < 4; ++i) {
        q  += dot4(cur[i], cur[i]);
        d2 += dot4(wv[i], cur[i]);
      }
      q  += __shfl_xor(q, 1);  q  += __shfl_xor(q, 2);  q  += __shfl_xor(q, 4);
      d2 += __shfl_xor(d2, 1); d2 += __shfl_xor(d2, 2); d2 += __shfl_xor(d2, 4);
      float e = __expf(d2 * rsqrtf(q * (1.f / 128.f) + 1e-8f));
      denom += e;
      #pragma unroll
      for (int i = 0; i < 4; ++i) hacc[i] += e * cur[i];
      if (s + 1 < NS) {
        #pragma unroll
        for (int i = 0; i < 4; ++i) cur[i] = nxt[i];
      }
    }
    if (ll > 0) {                       // running partial term (in regs)
      float q = 0.f, d2 = 0.f;
      #pragma unroll
      for (int i = 0; i < 4; ++i) {
        q  += dot4(part[i], part[i]);
        d2 += dot4(wv[i], part[i]);
      }
      q  += __shfl_xor(q, 1);  q  += __shfl_xor(q, 2);  q  += __shfl_xor(q, 4);
      d2 += __shfl_xor(d2, 1); d2 += __shfl_xor(d2, 2); d2 += __shfl_xor(d2, 4);
      float e = __expf(d2 * rsqrtf(q * (1.f / 128.f) + 1e-8f));
      denom += e;
      #pragma unroll
      for (int i = 0; i < 4; ++i) hacc[i] += e * part[i];
    }
    float inv = 1.0f / denom;
    #pragma unroll
    for (int i = 0; i < 4; ++i) hacc[i] *= inv;        // h (this wave's 8 rows)

    if (LAST && ll == 3) {                             // layer 15: MLP dead
      float* op = dst + toff;
      #pragma unroll
      for (int i = 0; i < 4; ++i) *(f32x4*)(op + 4 * i) = hacc[i];
      return;
    }

    // ---- LayerNorm -> bf16 A1 fragments (XOR-swizzled LDS) ---------------
    float sm = 0.f;
    #pragma unroll
    for (int i = 0; i < 4; ++i) sm += hacc[i].x + hacc[i].y + hacc[i].z + hacc[i].w;
    sm += __shfl_xor(sm, 1); sm += __shfl_xor(sm, 2); sm += __shfl_xor(sm, 4);
    float mu = sm * (1.f / 128.f);
    float sv = 0.f;
    #pragma unroll
    for (int i = 0; i < 4; ++i) {
      f32x4 d4 = hacc[i] - mu;
      sv += dot4(d4, d4);
    }
    sv += __shfl_xor(sv, 1); sv += __shfl_xor(sv, 2); sv += __shfl_xor(sv, 4);
    float rs = rsqrtf(sv * (1.f / 128.f) + 1e-5f);

    const float* gl = lng_all + layer * D + c0;
    const float* bl = lnb_all + layer * D + c0;
    f32x4 xn[4];
    #pragma unroll
    for (int i = 0; i < 4; ++i) {
      f32x4 g4 = *(const f32x4*)(gl + 4 * i);
      f32x4 b4 = *(const f32x4*)(bl + 4 * i);
      xn[i] = (hacc[i] - mu) * rs * g4 + b4;
    }
    {
      u16x8 pk0, pk1;
      pk0[0]=f2bf(xn[0].x); pk0[1]=f2bf(xn[0].y); pk0[2]=f2bf(xn[0].z); pk0[3]=f2bf(xn[0].w);
      pk0[4]=f2bf(xn[1].x); pk0[5]=f2bf(xn[1].y); pk0[6]=f2bf(xn[1].z); pk0[7]=f2bf(xn[1].w);
      pk1[0]=f2bf(xn[2].x); pk1[1]=f2bf(xn[2].y); pk1[2]=f2bf(xn[2].z); pk1[3]=f2bf(xn[2].w);
      pk1[4]=f2bf(xn[3].x); pk1[5]=f2bf(xn[3].y); pk1[6]=f2bf(xn[3].z); pk1[7]=f2bf(xn[3].w);
      int kk  = c8 >> 1;
      int hi0 = (c8 & 1) * 2;
      int FL0 = hi0 * 16 + r, FL1 = (hi0 + 1) * 16 + r;
      A1[kk * 64 + (FL0 ^ kk)] = pk0;      // xn[r][kk*32 + hi0*8 + 0..7]
      A1[kk * 64 + (FL1 ^ kk)] = pk1;      // xn[r][kk*32 + hi0*8 + 8..15]
    }
    __syncthreads();                                       // A1 ready

    bf16x8 a1f[4];
    #pragma unroll
    for (int k = 0; k < 4; ++k)
      a1f[k] = __builtin_bit_cast(bf16x8, A1[k * 64 + (l ^ k)]);

    // ---- GEMM1 (16x128 @ 128x256), this wave's N-half + GELU -> A2 -------
    const u16x8* W1f = (const u16x8*)(W1p + (size_t)layer * 32768);
    const float* b1l = b1_all + layer * 256;
    const f32x4 z4 = {0.f, 0.f, 0.f, 0.f};
    #pragma unroll
    for (int nti = 0; nti < 8; ++nti) {
      int nt = w2 * 8 + nti;
      f32x4 a = z4;
      #pragma unroll
      for (int k = 0; k < 4; ++k) {
        bf16x8 bf = __builtin_bit_cast(bf16x8, W1f[(k * 16 + nt) * 64 + l]);
        a = __builtin_amdgcn_mfma_f32_16x16x32_bf16(a1f[k], bf, a, 0, 0, 0);
      }
      float bb1 = b1l[nt * 16 + ln15];
      int kk2 = nt >> 1;
      int hi2 = ((nt & 1) << 1) + (ln15 >> 3);
      #pragma unroll
      for (int r4 = 0; r4 < 4; ++r4) {
        float g = fast_gelu(a[r4] + bb1);
        int FL = hi2 * 16 + lhi * 4 + r4;
        A2u[((kk2 * 64 + (FL ^ kk2)) << 3) + (l & 7)] = f2bf(g);
      }
    }
    __syncthreads();                                       // A2 ready

    bf16x8 a2f[8];
    #pragma unroll
    for (int k2 = 0; k2 < 8; ++k2)
      a2f[k2] = __builtin_bit_cast(bf16x8, A2[k2 * 64 + (l ^ k2)]);

    // ---- GEMM2 (16x256 @ 256x128), this wave's N-quarter -----------------
    const u16x8* W2f = (const u16x8*)(W2p + (size_t)layer * 32768);
    const float* b2l = b2_all + layer * D;
    #pragma unroll
    for (int nti = 0; nti < 4; ++nti) {
      int nt2 = w2 * 4 + nti;
      f32x4 a = z4;
      #pragma unroll
      for (int k2 = 0; k2 < 8; ++k2) {
        bf16x8 bf = __builtin_bit_cast(bf16x8, W2f[(k2 * 8 + nt2) * 64 + l]);
        a = __builtin_amdgcn_mfma_f32_16x16x32_bf16(a2f[k2], bf, a, 0, 0, 0);
      }
      int n = nt2 * 16 + ln15;
      float bb2 = b2l[n];
      int phys = (n & 96) + ((n + ((n >> 5) << 3)) & 31);   // bank-rotated col
      #pragma unroll
      for (int r4 = 0; r4 < 4; ++r4)
        SC[(lhi * 4 + r4) * 132 + phys] = a[r4] + bb2;
    }
    __syncthreads();                                       // v ready

    // ---- read v back in token layout, accumulate running partial ---------
    #pragma unroll
    for (int i = 0; i < 4; ++i) {
      int c = c0 + 4 * i;
      part[i] += *(const f32x4*)(SC + r * 132 + (c & 96) + ((c + ((c >> 5) << 3)) & 31));
    }
  }

  // ---- commit partial (P_b) in token layout, coalesced ---------------------
  float* op = dst + toff;
  #pragma unroll
  for (int i = 0; i < 4; ++i) *(f32x4*)(op + 4 * i) = part[i];
}

// ---------------------------------------------------------------------------
extern "C" void kernel_launch(void* const* d_in, const int* in_sizes, int n_in,
                              void* d_out, int out_size, void* d_ws, size_t ws_size,
                              hipStream_t stream)
{
  const float* emb = (const float*)d_in[0];
  const float* wv  = (const float*)d_in[1];
  const float* lng = (const float*)d_in[2];
  const float* lnb = (const float*)d_in[3];
  const float* W1  = (const float*)d_in[4];
  const float* b1  = (const float*)d_in[5];
  const float* W2  = (const float*)d_in[6];
  const float* b2  = (const float*)d_in[7];
  float* out = (float*)d_out;

  const int tokens = in_sizes[0] / D;                 // 65536
  const size_t tbytes = (size_t)tokens * D * sizeof(float);

  char* wsb = (char*)d_ws;
  float* P0 = (float*)(wsb + 0 * tbytes);
  float* P1 = (float*)(wsb + 1 * tbytes);
  float* P2 = (float*)(wsb + 2 * tbytes);
  unsigned short* W1p = (unsigned short*)(wsb + 3 * tbytes);
  unsigned short* W2p = W1p + 16 * 128 * 256;

  pack_weights<<<(16 * 128 * 256 * 2) / 256, 256, 0, stream>>>(W1, W2, W1p, W2p);

  const int grid = tokens / 16;                       // 4096 blocks of 128
  fused4<1, false><<<grid, 128, 0, stream>>>(emb, nullptr, nullptr, nullptr,
      wv, lng, lnb, W1p, b1, W2p, b2, P0);
  fused4<2, false><<<grid, 128, 0, stream>>>(emb, P0, nullptr, nullptr,
      wv, lng, lnb, W1p, b1, W2p, b2, P1);
  fused4<3, false><<<grid, 128, 0, stream>>>(emb, P0, P1, nullptr,
      wv, lng, lnb, W1p, b1, W2p, b2, P2);
  fused4<4, true ><<<grid, 128, 0, stream>>>(emb, P0, P1, P2,
      wv, lng, lnb, W1p, b1, W2p, b2, out);
}

// Round 9
// 774.435 us; speedup vs baseline: 2.0133x; 2.0133x over previous
//
#include <hip/hip_runtime.h>
#include <math.h>

// ---------------------------------------------------------------------------
// BlockAttnRes, round 9: r7 skeleton (4-wave/256-thr blocks, 32 tokens,
// 2x B-frag reuse, LDS-streamed A-frags) + r8 streaming mixture (no V[NS]
// register array) + NO waves_per_eu cap.
// r7 failure was pure scratch spill (V[4][4]+frag caches vs 128-VGPR cap);
// r8 proved sources can stream from L3 at zero time cost. Merge both.
// ---------------------------------------------------------------------------

typedef float    f32x4  __attribute__((ext_vector_type(4)));
typedef __bf16   bf16x8 __attribute__((ext_vector_type(8)));
typedef unsigned short u16x8 __attribute__((ext_vector_type(8)));

#define D 128

__device__ __forceinline__ unsigned short f2bf(float f) {
  unsigned int u = __builtin_bit_cast(unsigned int, f);
  u += 0x7fffu + ((u >> 16) & 1u);          // RNE
  return (unsigned short)(u >> 16);
}

__device__ __forceinline__ float dot4(f32x4 a, f32x4 b) {
  return a.x * b.x + a.y * b.y + a.z * b.z + a.w * b.w;
}

// exact-GELU via A&S 7.1.25 erf approx (|eps|<=2.5e-5, << bf16 rounding)
__device__ __forceinline__ float fast_gelu(float x) {
  float y = fabsf(x) * 0.70710678118654752f;
  float t = 1.0f / fmaf(0.47047f, y, 1.0f);
  float P = fmaf(fmaf(0.7478556f, t, -0.0958798f), t, 0.3480242f) * t;
  float E = __expf(-y * y);
  float er = fmaf(-P, E, 1.0f);             // erf(|x|/sqrt2)
  er = copysignf(er, x);
  return 0.5f * x * (1.0f + er);
}

// ---------------------------------------------------------------------------
// Pack W1/W2 (fp32 row-major) into bf16 MFMA B-fragment order:
// frag idx = ((kk*NT + nt)*64 + lane)*8 + j holds
//   B[k = kk*32 + (lane>>4)*8 + j][n = nt*16 + (lane&15)]
// ---------------------------------------------------------------------------
__global__ __launch_bounds__(256) void pack_weights(
    const float* __restrict__ W1, const float* __restrict__ W2,
    unsigned short* __restrict__ W1p, unsigned short* __restrict__ W2p)
{
  int t = blockIdx.x * 256 + threadIdx.x;
  if (t < 16 * 128 * 256) {
    int layer = t >> 15, r = t & 32767;
    int j = r & 7, lane = (r >> 3) & 63, nt = (r >> 9) & 15, kk = (r >> 13) & 3;
    int k = kk * 32 + ((lane >> 4) << 3) + j;
    int n = (nt << 4) + (lane & 15);
    W1p[t] = f2bf(W1[(layer << 15) + (k << 8) + n]);     // W1: [128][256]
  } else {
    int t2 = t - 16 * 128 * 256;
    int layer = t2 >> 15, r = t2 & 32767;
    int j = r & 7, lane = (r >> 3) & 63, nt = (r >> 9) & 7, kk = (r >> 12) & 7;
    int k = kk * 32 + ((lane >> 4) << 3) + j;
    int n = (nt << 4) + (lane & 15);
    W2p[t2] = f2bf(W2[(layer << 15) + (k << 7) + n]);    // W2: [256][128]
  }
}

// ---------------------------------------------------------------------------
// 4-layer fused kernel, 32 tokens per 256-thread block (4 waves).
// Sources streamed from L3 each layer (double-buffered regs, no V array).
// ---------------------------------------------------------------------------
template<int NS, bool LAST>
__global__ __launch_bounds__(256)
void fused4(const float* __restrict__ S0, const float* __restrict__ S1,
            const float* __restrict__ S2, const float* __restrict__ S3,
            const float* __restrict__ wv_all, const float* __restrict__ lng_all,
            const float* __restrict__ lnb_all,
            const unsigned short* __restrict__ W1p, const float* __restrict__ b1_all,
            const unsigned short* __restrict__ W2p, const float* __restrict__ b2_all,
            float* __restrict__ dst)
{
  __shared__ u16x8 A1f[2 * 4 * 64];   //  8 KB  A1 frags [m][kk][lane]
  __shared__ u16x8 A2f[2 * 8 * 64];   // 16 KB  A2 frags [m][kk2][lane]
  __shared__ float SC[32 * 132];      // 16.5 KB v-transpose scratch

  const int tid   = threadIdx.x;
  const int w     = tid >> 6;         // wave 0..3
  const int l     = tid & 63;
  const int tk8   = l >> 3;           // wave-local token 0..7
  const int c8    = l & 7;            // 16-col slice 0..7
  const int r_blk = w * 8 + tk8;      // block-local token 0..31
  const int c0    = c8 * 16;
  const int tok   = blockIdx.x * 32 + r_blk;
  const int m_own = r_blk >> 4;       // M-subtile of own token
  const int row16 = r_blk & 15;
  const int ln15  = l & 15, lhi = l >> 4;
  const size_t toff = (size_t)tok * D + c0;

  unsigned short* A2u = (unsigned short*)A2f;
  const float* srcs[4] = {S0, S1, S2, S3};

  f32x4 part[4];
  #pragma unroll
  for (int i = 0; i < 4; ++i) part[i] = f32x4{0.f, 0.f, 0.f, 0.f};

  const int L0 = (NS - 1) * 4;

  #pragma unroll 1
  for (int ll = 0; ll < 4; ++ll) {
    const int layer = L0 + ll;

    const float* wl = wv_all + layer * D + c0;
    f32x4 wv[4];
    #pragma unroll
    for (int i = 0; i < 4; ++i) wv[i] = *(const f32x4*)(wl + 4 * i);

    // ---- mixture softmax, sources STREAMED (double-buffered regs) --------
    // max-free: |logit| <= ~2.6, fp32 exp safe. RMS recomputed inline.
    float denom = 0.f;
    f32x4 hacc[4];
    #pragma unroll
    for (int i = 0; i < 4; ++i) hacc[i] = f32x4{0.f, 0.f, 0.f, 0.f};

    f32x4 cur[4], nxt[4];
    #pragma unroll
    for (int i = 0; i < 4; ++i) cur[i] = *(const f32x4*)(srcs[0] + toff + 4 * i);

    #pragma unroll
    for (int s = 0; s < NS; ++s) {
      if (s + 1 < NS) {                 // prefetch next source over compute
        #pragma unroll
        for (int i = 0; i < 4; ++i) nxt[i] = *(const f32x4*)(srcs[s + 1] + toff + 4 * i);
      }
      float q = 0.f, d2 = 0.f;
      #pragma unroll
      for (int i = 0; i < 4; ++i) {
        q  += dot4(cur[i], cur[i]);
        d2 += dot4(wv[i], cur[i]);
      }
      q  += __shfl_xor(q, 1);  q  += __shfl_xor(q, 2);  q  += __shfl_xor(q, 4);
      d2 += __shfl_xor(d2, 1); d2 += __shfl_xor(d2, 2); d2 += __shfl_xor(d2, 4);
      float e = __expf(d2 * rsqrtf(q * (1.f / 128.f) + 1e-8f));
      denom += e;
      #pragma unroll
      for (int i = 0; i < 4; ++i) hacc[i] += e * cur[i];
      if (s + 1 < NS) {
        #pragma unroll
        for (int i = 0; i < 4; ++i) cur[i] = nxt[i];
      }
    }
    if (ll > 0) {                       // running partial term (in regs)
      float q = 0.f, d2 = 0.f;
      #pragma unroll
      for (int i = 0; i < 4; ++i) {
        q  += dot4(part[i], part[i]);
        d2 += dot4(wv[i], part[i]);
      }
      q  += __shfl_xor(q, 1);  q  += __shfl_xor(q, 2);  q  += __shfl_xor(q, 4);
      d2 += __shfl_xor(d2, 1); d2 += __shfl_xor(d2, 2); d2 += __shfl_xor(d2, 4);
      float e = __expf(d2 * rsqrtf(q * (1.f / 128.f) + 1e-8f));
      denom += e;
      #pragma unroll
      for (int i = 0; i < 4; ++i) hacc[i] += e * part[i];
    }
    float inv = 1.0f / denom;
    #pragma unroll
    for (int i = 0; i < 4; ++i) hacc[i] *= inv;        // h (own 8 tokens)

    if (LAST && ll == 3) {                             // layer 15: MLP dead
      float* op = dst + toff;
      #pragma unroll
      for (int i = 0; i < 4; ++i) *(f32x4*)(op + 4 * i) = hacc[i];
      return;
    }

    // ---- LayerNorm -> bf16 A1 fragments (XOR-swizzled, block LDS) --------
    float sm = 0.f;
    #pragma unroll
    for (int i = 0; i < 4; ++i) sm += hacc[i].x + hacc[i].y + hacc[i].z + hacc[i].w;
    sm += __shfl_xor(sm, 1); sm += __shfl_xor(sm, 2); sm += __shfl_xor(sm, 4);
    float mu = sm * (1.f / 128.f);
    float sv = 0.f;
    #pragma unroll
    for (int i = 0; i < 4; ++i) {
      f32x4 d4 = hacc[i] - mu;
      sv += dot4(d4, d4);
    }
    sv += __shfl_xor(sv, 1); sv += __shfl_xor(sv, 2); sv += __shfl_xor(sv, 4);
    float rs = rsqrtf(sv * (1.f / 128.f) + 1e-5f);

    const float* gl = lng_all + layer * D + c0;
    const float* bl = lnb_all + layer * D + c0;
    f32x4 xn[4];
    #pragma unroll
    for (int i = 0; i < 4; ++i) {
      f32x4 g4 = *(const f32x4*)(gl + 4 * i);
      f32x4 b4 = *(const f32x4*)(bl + 4 * i);
      xn[i] = (hacc[i] - mu) * rs * g4 + b4;
    }
    {
      u16x8 pk0, pk1;
      pk0[0]=f2bf(xn[0].x); pk0[1]=f2bf(xn[0].y); pk0[2]=f2bf(xn[0].z); pk0[3]=f2bf(xn[0].w);
      pk0[4]=f2bf(xn[1].x); pk0[5]=f2bf(xn[1].y); pk0[6]=f2bf(xn[1].z); pk0[7]=f2bf(xn[1].w);
      pk1[0]=f2bf(xn[2].x); pk1[1]=f2bf(xn[2].y); pk1[2]=f2bf(xn[2].z); pk1[3]=f2bf(xn[2].w);
      pk1[4]=f2bf(xn[3].x); pk1[5]=f2bf(xn[3].y); pk1[6]=f2bf(xn[3].z); pk1[7]=f2bf(xn[3].w);
      int kk  = c8 >> 1;
      int hi0 = (c8 & 1) * 2;
      int FL0 = hi0 * 16 + row16, FL1 = (hi0 + 1) * 16 + row16;
      A1f[(m_own * 4 + kk) * 64 + (FL0 ^ kk)] = pk0;
      A1f[(m_own * 4 + kk) * 64 + (FL1 ^ kk)] = pk1;
    }
    __syncthreads();                                       // A1 ready

    // ---- GEMM1 (32x128 @ 128x256): wave w owns nt = {w,w+4,w+8,w+12} -----
    // B-frag loaded once, used for both M-subtiles. A-frags stream from LDS.
    const u16x8* W1f = (const u16x8*)(W1p + (size_t)layer * 32768);
    const float* b1l = b1_all + layer * 256;
    const f32x4 z4 = {0.f, 0.f, 0.f, 0.f};
    #pragma unroll
    for (int q = 0; q < 4; ++q) {
      const int nt = q * 4 + w;
      bf16x8 bf[4];
      #pragma unroll
      for (int kk = 0; kk < 4; ++kk)
        bf[kk] = __builtin_bit_cast(bf16x8, W1f[(kk * 16 + nt) * 64 + l]);
      const float bb1 = b1l[nt * 16 + ln15];
      const int kk2 = nt >> 1;
      const int hi2 = ((nt & 1) << 1) + (ln15 >> 3);
      #pragma unroll
      for (int m = 0; m < 2; ++m) {
        f32x4 a = z4;
        #pragma unroll
        for (int kk = 0; kk < 4; ++kk) {
          bf16x8 af = __builtin_bit_cast(bf16x8, A1f[(m * 4 + kk) * 64 + (l ^ kk)]);
          a = __builtin_amdgcn_mfma_f32_16x16x32_bf16(af, bf[kk], a, 0, 0, 0);
        }
        #pragma unroll
        for (int r4 = 0; r4 < 4; ++r4) {
          float g = fast_gelu(a[r4] + bb1);
          int FL = hi2 * 16 + lhi * 4 + r4;
          A2u[(((m * 8 + kk2) * 64) + (FL ^ kk2)) * 8 + (l & 7)] = f2bf(g);
        }
      }
    }
    __syncthreads();                                       // A2 ready

    // ---- GEMM2 (32x256 @ 256x128): wave w owns nt2 = {w, w+4} ------------
    const u16x8* W2f = (const u16x8*)(W2p + (size_t)layer * 32768);
    const float* b2l = b2_all + layer * D;
    #pragma unroll
    for (int p = 0; p < 2; ++p) {
      const int nt2 = p * 4 + w;
      bf16x8 bf[8];
      #pragma unroll
      for (int k2 = 0; k2 < 8; ++k2)
        bf[k2] = __builtin_bit_cast(bf16x8, W2f[(k2 * 8 + nt2) * 64 + l]);
      const int n = nt2 * 16 + ln15;
      const float bb2 = b2l[n];
      const int phys = (n & 96) + ((n + ((n >> 5) << 3)) & 31);  // bank rot
      #pragma unroll
      for (int m = 0; m < 2; ++m) {
        f32x4 a = z4;
        #pragma unroll
        for (int k2 = 0; k2 < 8; ++k2) {
          bf16x8 af = __builtin_bit_cast(bf16x8, A2f[(m * 8 + k2) * 64 + (l ^ k2)]);
          a = __builtin_amdgcn_mfma_f32_16x16x32_bf16(af, bf[k2], a, 0, 0, 0);
        }
        #pragma unroll
        for (int r4 = 0; r4 < 4; ++r4)
          SC[(m * 16 + lhi * 4 + r4) * 132 + phys] = a[r4] + bb2;
      }
    }
    __syncthreads();                                       // v ready

    // ---- read v back in token layout, accumulate running partial ---------
    #pragma unroll
    for (int i = 0; i < 4; ++i) {
      int c = c0 + 4 * i;
      part[i] += *(const f32x4*)(SC + r_blk * 132 + (c & 96) + ((c + ((c >> 5) << 3)) & 31));
    }
    __syncthreads();                                       // SC consumed
  }

  // ---- commit partial (P_b) in token layout, coalesced ---------------------
  float* op = dst + toff;
  #pragma unroll
  for (int i = 0; i < 4; ++i) *(f32x4*)(op + 4 * i) = part[i];
}

// ---------------------------------------------------------------------------
extern "C" void kernel_launch(void* const* d_in, const int* in_sizes, int n_in,
                              void* d_out, int out_size, void* d_ws, size_t ws_size,
                              hipStream_t stream)
{
  const float* emb = (const float*)d_in[0];
  const float* wv  = (const float*)d_in[1];
  const float* lng = (const float*)d_in[2];
  const float* lnb = (const float*)d_in[3];
  const float* W1  = (const float*)d_in[4];
  const float* b1  = (const float*)d_in[5];
  const float* W2  = (const float*)d_in[6];
  const float* b2  = (const float*)d_in[7];
  float* out = (float*)d_out;

  const int tokens = in_sizes[0] / D;                 // 65536
  const size_t tbytes = (size_t)tokens * D * sizeof(float);

  char* wsb = (char*)d_ws;
  float* P0 = (float*)(wsb + 0 * tbytes);
  float* P1 = (float*)(wsb + 1 * tbytes);
  float* P2 = (float*)(wsb + 2 * tbytes);
  unsigned short* W1p = (unsigned short*)(wsb + 3 * tbytes);
  unsigned short* W2p = W1p + 16 * 128 * 256;

  pack_weights<<<(16 * 128 * 256 * 2) / 256, 256, 0, stream>>>(W1, W2, W1p, W2p);

  const int grid = tokens / 32;                       // 2048 blocks of 256
  fused4<1, false><<<grid, 256, 0, stream>>>(emb, nullptr, nullptr, nullptr,
      wv, lng, lnb, W1p, b1, W2p, b2, P0);
  fused4<2, false><<<grid, 256, 0, stream>>>(emb, P0, nullptr, nullptr,
      wv, lng, lnb, W1p, b1, W2p, b2, P1);
  fused4<3, false><<<grid, 256, 0, stream>>>(emb, P0, P1, nullptr,
      wv, lng, lnb, W1p, b1, W2p, b2, P2);
  fused4<4, true ><<<grid, 256, 0, stream>>>(emb, P0, P1, P2,
      wv, lng, lnb, W1p, b1, W2p, b2, out);
}